// Round 17
// baseline (60.960 us; speedup 1.0000x reference)
//
#include <hip/hip_runtime.h>
#include <hip/hip_bf16.h>
#include <math.h>

// Problem dims (fixed by reference): B=64, N=32, S=1024, D=128
#define NB 64
#define NTOK 32
#define NS 1024
#define ND 128

typedef __attribute__((ext_vector_type(8))) short short8;    // 8 x bf16 (4 VGPR)
typedef __attribute__((ext_vector_type(16))) float f32x16;   // 32x32 MFMA acc

// RTNE pack via v_cvt_pk_bf16_f32. q, doc, neg ALL use this same function, so
// any pairing-order quirk cancels in the MFMA dot product.
__device__ __forceinline__ short8 cvt8(float4 a, float4 b) {
    union { unsigned int u[4]; short8 s; } r;
    asm("v_cvt_pk_bf16_f32 %0, %1, %2" : "=v"(r.u[0]) : "v"(a.x), "v"(a.y));
    asm("v_cvt_pk_bf16_f32 %0, %1, %2" : "=v"(r.u[1]) : "v"(a.z), "v"(a.w));
    asm("v_cvt_pk_bf16_f32 %0, %1, %2" : "=v"(r.u[2]) : "v"(b.x), "v"(b.y));
    asm("v_cvt_pk_bf16_f32 %0, %1, %2" : "=v"(r.u[3]) : "v"(b.z), "v"(b.w));
    return r.s;
}

// 32x32x16 fragment map (A and B identical; permutation errors cancel, and the
// consumer only needs sum-over-n / max-over-s so bijectivity suffices):
// tile = 32 rows x 128 k, stored [kstep(8)][lane(64)][8 bf16]:
//   lane = row(0..31) + 32*hi,  k = kstep*16 + 8*hi + j.
// Convert tile = 32x128 fp32 -> this layout, LDS-bounced (both sides coalesced).
__global__ __launch_bounds__(256) void convert_qd(const float* __restrict__ q,
                                                  const float* __restrict__ dc,
                                                  short* __restrict__ qf,
                                                  short* __restrict__ df) {
    __shared__ short lds[2][4096];
    int t = threadIdx.x;
    int row = t >> 3, kq = t & 7;  // row in [0,32), kstep in [0,8)
#pragma unroll
    for (int half = 0; half < 2; ++half) {
        int tile = blockIdx.x * 2 + half;  // [0,64) q | [64,2112) doc
        const float* in = (tile < 64) ? q : dc;
        int rel = (tile < 64) ? tile : tile - 64;
        const float* src = in + (size_t)rel * 4096 + row * 128 + kq * 16;
        float4 f0 = ((const float4*)src)[0], f1 = ((const float4*)src)[1];
        float4 f2 = ((const float4*)src)[2], f3 = ((const float4*)src)[3];
        *(short8*)(&lds[half][kq * 512 + row * 8]) = cvt8(f0, f1);         // hi=0
        *(short8*)(&lds[half][kq * 512 + (row + 32) * 8]) = cvt8(f2, f3);  // hi=1
    }
    __syncthreads();
#pragma unroll
    for (int half = 0; half < 2; ++half) {
        int tile = blockIdx.x * 2 + half;
        short* out = (tile < 64) ? qf : df;
        int rel = (tile < 64) ? tile : tile - 64;
        *(short8*)(out + (size_t)rel * 4096 + t * 16) = *(const short8*)(&lds[half][t * 16]);
        *(short8*)(out + (size_t)rel * 4096 + t * 16 + 8) = *(const short8*)(&lds[half][t * 16 + 8]);
    }
}

// T3+T4 maxsim with 32x32x16 MFMA (2495 TF pipe vs 2075 for 16x16; half the
// instruction count at same FLOP). Skeleton = R14 (best measured): grid
// (c=64, bg=4) = 256 blocks = 1/CU, 8 waves, 2 b's/wave; 16 chunks x 64 doc
// rows; 4-deep LDS ring; 3 chunks DMA in flight; counted vmcnt never 0 in
// steady state. All register arrays statically indexed (rule #20).
// C map (guide-verified m74/m101): col(=s)=lane&31, row(=n)=(r&3)+8*(r>>2)+4*(lane>>5).
__global__ __launch_bounds__(512, 1) void maxsim_main(const short* __restrict__ qf,
                                                      const short* __restrict__ df,
                                                      const float* __restrict__ ng,
                                                      float* __restrict__ score_part,
                                                      float* __restrict__ neg_part) {
    int c = blockIdx.x;
    int bg = blockIdx.y;
    int t = threadIdx.x;
    int w = t >> 6, l = t & 63;
    int b0 = bg * 16 + w * 2;  // this wave: b0, b0+1

    __shared__ alignas(16) short lds[4][8192];  // 4 x 16KB ring (2 tiles each)
    const short* dbase = df + (size_t)c * (NS * ND);

    // q fragments: qa[bb][kstep] -> 2 x 8 x 4 VGPR = 64 VGPR (static idx only)
    short8 qa[2][8];
#pragma unroll
    for (int bb = 0; bb < 2; ++bb)
#pragma unroll
        for (int k = 0; k < 8; ++k)
            qa[bb][k] = *(const short8*)(qf + (size_t)(b0 + bb) * 4096 + k * 512 + l * 8);

    // fused neg partial: wave covers (b = b0 + (c&1), s-tile = c>>1) exactly once
    // across the grid. fp32 read + inline cvt; static qa index via branch.
    {
        int stile = c >> 1;
        const float* nbase0 =
            ng + ((size_t)(b0 + (c & 1)) * NS + stile * 32 + (l & 31)) * ND + 8 * (l >> 5);
        short8 nb[8];
#pragma unroll
        for (int k = 0; k < 8; ++k) {
            const float* sp = nbase0 + k * 16;
            nb[k] = cvt8(((const float4*)sp)[0], ((const float4*)sp)[1]);
        }
        f32x16 acc;
#pragma unroll
        for (int r = 0; r < 16; ++r) acc[r] = 0.f;
        if ((c & 1) == 0) {
#pragma unroll
            for (int k = 0; k < 8; ++k)
                acc = __builtin_amdgcn_mfma_f32_32x32x16_bf16(qa[0][k], nb[k], acc, 0, 0, 0);
        } else {
#pragma unroll
            for (int k = 0; k < 8; ++k)
                acc = __builtin_amdgcn_mfma_f32_32x32x16_bf16(qa[1][k], nb[k], acc, 0, 0, 0);
        }
#pragma unroll
        for (int r = 0; r < 16; ++r) {  // rowmax over s = across lanes sharing l>>5
            float v = acc[r];
            v = fmaxf(v, __shfl_xor(v, 1));
            v = fmaxf(v, __shfl_xor(v, 2));
            v = fmaxf(v, __shfl_xor(v, 4));
            v = fmaxf(v, __shfl_xor(v, 8));
            v = fmaxf(v, __shfl_xor(v, 16));
            if ((l & 31) == 0)
                neg_part[(stile * 64 + (b0 + (c & 1))) * 32 +
                         ((r & 3) + 8 * (r >> 2) + 4 * (l >> 5))] = v;
        }
    }

    // Normalize vmcnt to exactly 0 so the counted scheme below is exact.
    asm volatile("s_waitcnt vmcnt(0) lgkmcnt(0)" ::: "memory");
    __builtin_amdgcn_sched_barrier(0);

    // DMA-stage chunk K into ring slot K&3: 512 threads x 2 x 16B, linear.
#define STAGE(K)                                                                 \
    {                                                                            \
        const short* _s = dbase + (K) * 8192 + t * 8;                            \
        short* _d = &lds[(K) & 3][t * 8];                                        \
        _Pragma("unroll") for (int i = 0; i < 2; ++i)                            \
            __builtin_amdgcn_global_load_lds(                                    \
                (const __attribute__((address_space(1))) void*)(_s + i * 4096),  \
                (__attribute__((address_space(3))) void*)(_d + i * 4096),        \
                16, 0, 0);                                                       \
    }

    STAGE(0) STAGE(1) STAGE(2)  // 6 loads/thread in flight

    f32x16 vmax[2];
#pragma unroll
    for (int bb = 0; bb < 2; ++bb)
#pragma unroll
        for (int r = 0; r < 16; ++r) vmax[bb][r] = -INFINITY;

    for (int ch = 0; ch < 16; ++ch) {
        // chunk ch resident when <= 2 chunks (4 loads) remain outstanding
        if (ch <= 13) {
            asm volatile("s_waitcnt vmcnt(4)" ::: "memory");
        } else if (ch == 14) {
            asm volatile("s_waitcnt vmcnt(2)" ::: "memory");
        } else {
            asm volatile("s_waitcnt vmcnt(0)" ::: "memory");
        }
        __builtin_amdgcn_sched_barrier(0);
        __builtin_amdgcn_s_barrier();  // chunk ch resident; slot (ch+3)&3 free
        if (ch + 3 < 16) STAGE(ch + 3)

        const short* buf = &lds[ch & 3][0];
#pragma unroll
        for (int ss = 0; ss < 2; ++ss) {  // 2 s-tiles of 32 docs
            f32x16 acc[2];
#pragma unroll
            for (int bb = 0; bb < 2; ++bb)
#pragma unroll
                for (int r = 0; r < 16; ++r) acc[bb][r] = 0.f;
            __builtin_amdgcn_s_setprio(1);
#pragma unroll
            for (int k = 0; k < 8; ++k) {
                short8 bfv = *(const short8*)(buf + ss * 4096 + k * 512 + l * 8);
                acc[0] = __builtin_amdgcn_mfma_f32_32x32x16_bf16(qa[0][k], bfv, acc[0], 0, 0, 0);
                acc[1] = __builtin_amdgcn_mfma_f32_32x32x16_bf16(qa[1][k], bfv, acc[1], 0, 0, 0);
            }
            __builtin_amdgcn_s_setprio(0);
#pragma unroll
            for (int bb = 0; bb < 2; ++bb)
#pragma unroll
                for (int r = 0; r < 16; ++r)
                    vmax[bb][r] = fmaxf(vmax[bb][r], acc[bb][r]);
        }
    }
#undef STAGE

    // per-n rowmax -> score_part[(c*64 + b)*32 + n]; n = (r&3)+8*(r>>2)+4*(l>>5)
#pragma unroll
    for (int bb = 0; bb < 2; ++bb)
#pragma unroll
        for (int r = 0; r < 16; ++r) {
            float v = vmax[bb][r];
            v = fmaxf(v, __shfl_xor(v, 1));
            v = fmaxf(v, __shfl_xor(v, 2));
            v = fmaxf(v, __shfl_xor(v, 4));
            v = fmaxf(v, __shfl_xor(v, 8));
            v = fmaxf(v, __shfl_xor(v, 16));
            if ((l & 31) == 0)
                score_part[((c * 64) + (b0 + bb)) * 32 +
                           ((r & 3) + 8 * (r >> 2) + 4 * (l >> 5))] = v;
        }
}

// Per-b: scores[b][c] = sum_n score_part (c = lane; n-permutation irrelevant),
// reduce neg over 32 s-tiles, CE + softplus -> bloss[b]. 64 blocks x 64 thr.
__global__ __launch_bounds__(64) void reduce_b(const float* __restrict__ score_part,
                                               const float* __restrict__ neg_part,
                                               const int* __restrict__ offp,
                                               float* __restrict__ bloss) {
    int b = blockIdx.x;
    int c = threadIdx.x;  // one wave
    const float4* p0 = (const float4*)(score_part + (c * 64 + b) * 32);
    float s = 0.f;
#pragma unroll
    for (int j = 0; j < 8; ++j) {
        float4 a = p0[j];
        s += a.x + a.y + a.z + a.w;
    }
    // neg: elementwise max over 32 s-tiles (lanes 32..63 duplicate reads; max-safe)
    float v[32];
    {
        const float4* np = (const float4*)(neg_part + ((c & 31) * 64 + b) * 32);
#pragma unroll
        for (int j = 0; j < 8; ++j) {
            float4 a = np[j];
            v[j * 4] = a.x; v[j * 4 + 1] = a.y; v[j * 4 + 2] = a.z; v[j * 4 + 3] = a.w;
        }
    }
#pragma unroll
    for (int off = 1; off < 64; off <<= 1)
#pragma unroll
        for (int j = 0; j < 32; ++j) v[j] = fmaxf(v[j], __shfl_xor(v[j], off));
    float negs = 0.f;
#pragma unroll
    for (int j = 0; j < 32; ++j) negs += v[j];

    const float invT = 50.0f;
    float m = s;
#pragma unroll
    for (int off = 1; off < 64; off <<= 1) m = fmaxf(m, __shfl_xor(m, off));
    float e = expf((s - m) * invT);
#pragma unroll
    for (int off = 1; off < 64; off <<= 1) e += __shfl_xor(e, off);
    float lse = m * invT + logf(e);
    int label = offp[0] + b;
    label = label < 0 ? 0 : (label > 63 ? 63 : label);
    float slabel = __shfl(s, label);
    float pos = __shfl(s, b);
    if (c == 0) {
        float x = (negs - pos) * invT;
        float sp = fmaxf(x, 0.f) + log1pf(expf(-fabsf(x)));
        bloss[b] = sp + lse - slabel * invT;
    }
}

__global__ __launch_bounds__(64) void final_sum(const float* __restrict__ bloss,
                                                float* __restrict__ out) {
    float v = bloss[threadIdx.x];
#pragma unroll
    for (int off = 1; off < 64; off <<= 1) v += __shfl_xor(v, off);
    if (threadIdx.x == 0) out[0] = v * (0.5f / 64.f);
}

extern "C" void kernel_launch(void* const* d_in, const int* in_sizes, int n_in,
                              void* d_out, int out_size, void* d_ws, size_t ws_size,
                              hipStream_t stream) {
    const float* q = (const float*)d_in[0];
    const float* dc = (const float*)d_in[1];
    const float* ng = (const float*)d_in[2];
    const int* offp = (const int*)d_in[3];
    float* out = (float*)d_out;

    // ws: qf 512KB @0 | df 16MB @0x80000 | neg_part 256KB @0x1080000 |
    //     score_part 512KB @0x1100000 | bloss @0x1180000
    char* ws = (char*)d_ws;
    short* qf = (short*)(ws);
    short* df = (short*)(ws + 0x80000);
    float* neg_part = (float*)(ws + 0x1080000);
    float* score_part = (float*)(ws + 0x1100000);
    float* bloss = (float*)(ws + 0x1180000);
    if (ws_size < 0x1180200) return;

    convert_qd<<<1056, 256, 0, stream>>>(q, dc, qf, df);
    maxsim_main<<<dim3(64, 4), 512, 0, stream>>>(qf, df, ng, score_part, neg_part);
    reduce_b<<<64, 64, 0, stream>>>(score_part, neg_part, offp, bloss);
    final_sum<<<1, 64, 0, stream>>>(bloss, out);
}

// Round 18
// 50.922 us; speedup vs baseline: 1.1971x; 1.1971x over previous
//
#include <hip/hip_runtime.h>
#include <hip/hip_bf16.h>
#include <math.h>

// Problem dims (fixed by reference): B=64, N=32, S=1024, D=128
#define NB 64
#define NTOK 32
#define NS 1024
#define ND 128

typedef __attribute__((ext_vector_type(8))) short short8;  // 8 x bf16
typedef __attribute__((ext_vector_type(4))) float f32x4;

__device__ __forceinline__ unsigned short f2bf(float x) {
    unsigned int u = __builtin_bit_cast(unsigned int, x);
    u += 0x7fffu + ((u >> 16) & 1u);  // round-to-nearest-even
    return (unsigned short)(u >> 16);
}

// RTNE pack; used for the once-read neg inline convert (same rounding as f2bf).
__device__ __forceinline__ short8 cvt8(float4 a, float4 b) {
    union { unsigned int u[4]; short8 s; } r;
    asm("v_cvt_pk_bf16_f32 %0, %1, %2" : "=v"(r.u[0]) : "v"(a.x), "v"(a.y));
    asm("v_cvt_pk_bf16_f32 %0, %1, %2" : "=v"(r.u[1]) : "v"(a.z), "v"(a.w));
    asm("v_cvt_pk_bf16_f32 %0, %1, %2" : "=v"(r.u[2]) : "v"(b.x), "v"(b.y));
    asm("v_cvt_pk_bf16_f32 %0, %1, %2" : "=v"(r.u[3]) : "v"(b.z), "v"(b.w));
    return r.s;
}

// Convert ONLY q + doc (reused many times; neg converted inline in maxsim).
// Tile = 16x128 fp32 -> fragment layout [tile][ks(4)][lane(64)][8] bf16;
// lane l = row (l&15), k = ks*32+8*(l>>4)+j. LDS-bounced, both sides coalesced.
__global__ __launch_bounds__(256) void convert_qd(const float* __restrict__ q,
                                                  const float* __restrict__ dc,
                                                  short* __restrict__ qf,
                                                  short* __restrict__ df) {
    __shared__ short lds[2][2048];
    int t = threadIdx.x;
    int row = t >> 4, g = t & 15;
    int slot = ((g >> 2) * 64 + (g & 3) * 16 + row);
#pragma unroll
    for (int half = 0; half < 2; ++half) {
        int tile = blockIdx.x * 2 + half;  // [0,128) q | [128,4224) doc
        const float* in = (tile < 128) ? q : dc;
        int rel = (tile < 128) ? tile : tile - 128;
        const float4* src = (const float4*)(in + (size_t)rel * 2048 + t * 8);
        float4 a = src[0], b = src[1];
        float f[8] = {a.x, a.y, a.z, a.w, b.x, b.y, b.z, b.w};
        short8 r;
#pragma unroll
        for (int j = 0; j < 8; ++j) r[j] = (short)f2bf(f[j]);
        *(short8*)(&lds[half][slot * 8]) = r;
    }
    __syncthreads();
#pragma unroll
    for (int half = 0; half < 2; ++half) {
        int tile = blockIdx.x * 2 + half;
        short* out = (tile < 128) ? qf : df;
        int rel = (tile < 128) ? tile : tile - 128;
        *(short8*)(out + (size_t)rel * 2048 + t * 8) = *(const short8*)(&lds[half][t * 8]);
    }
}

// T3+T4 maxsim, barrier-amortized: chunk = 128 doc rows (32KB), 8 chunks,
// 3-deep ring (96KB LDS) -> halves barrier events vs R14 (8 vs 16) and gives
// 128 MFMA/wave between barriers. Grid (c=64, bg=4) = 256 blocks = 1/CU;
// XCD = c%8. 8 waves, 2 b's/wave (qa = 64 VGPR, no-spill shape). 2 chunks of
// DMA in flight; counted vmcnt never 0 in steady state. No setprio (m190:
// null-to-negative on barrier-lockstep structures).
__global__ __launch_bounds__(512, 1) void maxsim_main(const short* __restrict__ qf,
                                                      const short* __restrict__ df,
                                                      const float* __restrict__ ng,
                                                      float* __restrict__ score_part,
                                                      float* __restrict__ neg_part) {
    int c = blockIdx.x;
    int bg = blockIdx.y;
    int t = threadIdx.x;
    int w = t >> 6, l = t & 63;
    int b0 = bg * 16 + w * 2;  // this wave: b0, b0+1

    __shared__ alignas(16) short lds[3][16384];  // 3 x 32KB ring
    const short* dbase = df + (size_t)c * (NS * ND);
    f32x4 zero = {0.f, 0.f, 0.f, 0.f};

    // q fragments: [bb][mtile][kstep] -> 64 VGPR
    short8 qa[2][2][4];
#pragma unroll
    for (int bb = 0; bb < 2; ++bb)
#pragma unroll
        for (int m = 0; m < 2; ++m)
#pragma unroll
            for (int ks = 0; ks < 4; ++ks)
                qa[bb][m][ks] =
                    *(const short8*)(qf + (((b0 + bb) * 2 + m) * 4 + ks) * 512 + l * 8);

    // fused neg partial: tile (b, s-chunk c) of q[b]·neg[b], fp32 read + inline cvt
#pragma unroll
    for (int bb = 0; bb < 2; ++bb) {
        const float* nt =
            ng + ((size_t)((b0 + bb) * 64 + c) * 16 + (l & 15)) * ND + 8 * (l >> 4);
        short8 nb[4];
#pragma unroll
        for (int ks = 0; ks < 4; ++ks) {
            const float* sp = nt + ks * 32;
            nb[ks] = cvt8(((const float4*)sp)[0], ((const float4*)sp)[1]);
        }
#pragma unroll
        for (int m = 0; m < 2; ++m) {
            f32x4 acc = zero;
#pragma unroll
            for (int ks = 0; ks < 4; ++ks)
                acc = __builtin_amdgcn_mfma_f32_16x16x32_bf16(qa[bb][m][ks], nb[ks], acc, 0, 0, 0);
#pragma unroll
            for (int r = 0; r < 4; ++r) {  // rowmax over s within 16-lane group
                float v = acc[r];
                v = fmaxf(v, __shfl_xor(v, 1));
                v = fmaxf(v, __shfl_xor(v, 2));
                v = fmaxf(v, __shfl_xor(v, 4));
                v = fmaxf(v, __shfl_xor(v, 8));
                if ((l & 15) == 0)
                    neg_part[(c * 64 + (b0 + bb)) * 32 + m * 16 + (l >> 4) * 4 + r] = v;
            }
        }
    }

    // Normalize vmcnt to exactly 0 so the counted scheme below is exact.
    asm volatile("s_waitcnt vmcnt(0) lgkmcnt(0)" ::: "memory");
    __builtin_amdgcn_sched_barrier(0);

    // DMA-stage chunk K (32KB) into ring slot K%3: 512 thr x 4 issues x 16B, linear.
#define STAGE(K)                                                                 \
    {                                                                            \
        const short* _s = dbase + (K) * 16384 + t * 8;                           \
        short* _d = &lds[(K) % 3][t * 8];                                        \
        _Pragma("unroll") for (int i = 0; i < 4; ++i)                            \
            __builtin_amdgcn_global_load_lds(                                    \
                (const __attribute__((address_space(1))) void*)(_s + i * 4096),  \
                (__attribute__((address_space(3))) void*)(_d + i * 4096),        \
                16, 0, 0);                                                       \
    }

    STAGE(0) STAGE(1)  // 8 loads/thread in flight (2 chunks)

    f32x4 vmax[2][2];
#pragma unroll
    for (int bb = 0; bb < 2; ++bb)
#pragma unroll
        for (int m = 0; m < 2; ++m)
#pragma unroll
            for (int r = 0; r < 4; ++r) vmax[bb][m][r] = -INFINITY;

    for (int ch = 0; ch < 8; ++ch) {
        // chunk ch resident when <= 1 chunk (4 loads) remains outstanding
        if (ch < 7) {
            asm volatile("s_waitcnt vmcnt(4)" ::: "memory");
        } else {
            asm volatile("s_waitcnt vmcnt(0)" ::: "memory");
        }
        __builtin_amdgcn_sched_barrier(0);
        __builtin_amdgcn_s_barrier();  // chunk ch resident; all waves finished
                                       // reading chunk ch-1 -> slot (ch+2)%3 free
        if (ch + 2 < 8) STAGE(ch + 2)

        const short* buf = &lds[ch % 3][0];
#pragma unroll
        for (int ss = 0; ss < 8; ++ss) {  // 8 s-subtiles of 16 docs
            short8 bf[4];
#pragma unroll
            for (int ks = 0; ks < 4; ++ks)
                bf[ks] = *(const short8*)(buf + ((ss * 4 + ks) * 64 + l) * 8);
#pragma unroll
            for (int bb = 0; bb < 2; ++bb)
#pragma unroll
                for (int m = 0; m < 2; ++m) {
                    f32x4 acc = zero;
#pragma unroll
                    for (int ks = 0; ks < 4; ++ks)
                        acc = __builtin_amdgcn_mfma_f32_16x16x32_bf16(qa[bb][m][ks], bf[ks], acc, 0, 0, 0);
#pragma unroll
                    for (int r = 0; r < 4; ++r)
                        vmax[bb][m][r] = fmaxf(vmax[bb][m][r], acc[r]);
                }
        }
    }
#undef STAGE

    // per-n rowmax -> score_part[(c*64 + b)*32 + n]
#pragma unroll
    for (int bb = 0; bb < 2; ++bb)
#pragma unroll
        for (int m = 0; m < 2; ++m)
#pragma unroll
            for (int r = 0; r < 4; ++r) {
                float v = vmax[bb][m][r];
                v = fmaxf(v, __shfl_xor(v, 1));
                v = fmaxf(v, __shfl_xor(v, 2));
                v = fmaxf(v, __shfl_xor(v, 4));
                v = fmaxf(v, __shfl_xor(v, 8));
                if ((l & 15) == 0)
                    score_part[((c * 64) + (b0 + bb)) * 32 + m * 16 + (l >> 4) * 4 + r] = v;
            }
}

// Per-b: scores[b][c] = sum_n score_part (c = lane), reduce neg over c,
// CE + softplus -> bloss[b]. 64 blocks x 64 threads.
__global__ __launch_bounds__(64) void reduce_b(const float* __restrict__ score_part,
                                               const float* __restrict__ neg_part,
                                               const int* __restrict__ offp,
                                               float* __restrict__ bloss) {
    int b = blockIdx.x;
    int c = threadIdx.x;  // one wave
    const float4* p0 = (const float4*)(score_part + (c * 64 + b) * 32);
    float s = 0.f;
#pragma unroll
    for (int j = 0; j < 8; ++j) {
        float4 a = p0[j];
        s += a.x + a.y + a.z + a.w;
    }
    // neg: elementwise max over c of neg_part[c][b][n], then sum over n
    float v[32];
    {
        const float4* np = (const float4*)(neg_part + (c * 64 + b) * 32);
#pragma unroll
        for (int j = 0; j < 8; ++j) {
            float4 a = np[j];
            v[j * 4] = a.x; v[j * 4 + 1] = a.y; v[j * 4 + 2] = a.z; v[j * 4 + 3] = a.w;
        }
    }
#pragma unroll
    for (int off = 1; off < 64; off <<= 1)
#pragma unroll
        for (int j = 0; j < 32; ++j) v[j] = fmaxf(v[j], __shfl_xor(v[j], off));
    float negs = 0.f;
#pragma unroll
    for (int j = 0; j < 32; ++j) negs += v[j];

    const float invT = 50.0f;
    float m = s;
#pragma unroll
    for (int off = 1; off < 64; off <<= 1) m = fmaxf(m, __shfl_xor(m, off));
    float e = expf((s - m) * invT);
#pragma unroll
    for (int off = 1; off < 64; off <<= 1) e += __shfl_xor(e, off);
    float lse = m * invT + logf(e);
    int label = offp[0] + b;
    label = label < 0 ? 0 : (label > 63 ? 63 : label);
    float slabel = __shfl(s, label);
    float pos = __shfl(s, b);
    if (c == 0) {
        float x = (negs - pos) * invT;
        float sp = fmaxf(x, 0.f) + log1pf(expf(-fabsf(x)));
        bloss[b] = sp + lse - slabel * invT;
    }
}

__global__ __launch_bounds__(64) void final_sum(const float* __restrict__ bloss,
                                                float* __restrict__ out) {
    float v = bloss[threadIdx.x];
#pragma unroll
    for (int off = 1; off < 64; off <<= 1) v += __shfl_xor(v, off);
    if (threadIdx.x == 0) out[0] = v * (0.5f / 64.f);
}

extern "C" void kernel_launch(void* const* d_in, const int* in_sizes, int n_in,
                              void* d_out, int out_size, void* d_ws, size_t ws_size,
                              hipStream_t stream) {
    const float* q = (const float*)d_in[0];
    const float* dc = (const float*)d_in[1];
    const float* ng = (const float*)d_in[2];
    const int* offp = (const int*)d_in[3];
    float* out = (float*)d_out;

    // ws: qf 512KB @0 | df 16MB @0x80000 | neg_part 512KB @0x1080000 |
    //     score_part 512KB @0x1100000 | bloss @0x1180000
    char* ws = (char*)d_ws;
    short* qf = (short*)(ws);
    short* df = (short*)(ws + 0x80000);
    float* neg_part = (float*)(ws + 0x1080000);
    float* score_part = (float*)(ws + 0x1100000);
    float* bloss = (float*)(ws + 0x1180000);
    if (ws_size < 0x1180200) return;

    convert_qd<<<2112, 256, 0, stream>>>(q, dc, qf, df);
    maxsim_main<<<dim3(64, 4), 512, 0, stream>>>(qf, df, ng, score_part, neg_part);
    reduce_b<<<64, 64, 0, stream>>>(score_part, neg_part, offp, bloss);
    final_sum<<<1, 64, 0, stream>>>(bloss, out);
}